// Round 14
// baseline (263.766 us; speedup 1.0000x reference)
//
#include <hip/hip_runtime.h>
#include <hip/hip_fp16.h>
#include <math.h>

#define TPB 256
#define BKT_SHIFT 9
#define BKT_N 512              // nodes per bucket
#define NB_MAX 256             // max buckets (n <= 131072)
#define CHUNK 2048             // edges per block-chunk in bucket_scatter
#define CAP   24576            // padded packed-region capacity per bucket
#define Y_SCALE 16.0f
#define Y_INV_SCALE (1.0f / 16.0f)

typedef short bf16x8 __attribute__((ext_vector_type(8)));
typedef float f32x4  __attribute__((ext_vector_type(4)));

static __device__ inline unsigned short f2bf(float f) {
    union { float f; unsigned u; } v; v.f = f;
    unsigned r = v.u + 0x7FFF + ((v.u >> 16) & 1);
    return (unsigned short)(r >> 16);
}

static __device__ inline unsigned char f2fp8(float x) {
    int p = __builtin_amdgcn_cvt_pk_fp8_f32(x, x, 0, false);
    return (unsigned char)(p & 0xFF);
}

static __device__ inline void acc_word(float* a, unsigned u) {
    a[0] += __builtin_amdgcn_cvt_f32_fp8(u, 0);
    a[1] += __builtin_amdgcn_cvt_f32_fp8(u, 1);
    a[2] += __builtin_amdgcn_cvt_f32_fp8(u, 2);
    a[3] += __builtin_amdgcn_cvt_f32_fp8(u, 3);
}

// ------------------------------------------- setup: W->bf16^T x3, cursor init, pooled=0
__global__ __launch_bounds__(256) void setup_kernel(
    const float* __restrict__ W1, unsigned short* __restrict__ Wt1,
    const float* __restrict__ W2, unsigned short* __restrict__ Wt2,
    const float* __restrict__ W3, unsigned short* __restrict__ Wt3,
    int* __restrict__ bcursor, float* __restrict__ pooled, int nbkt)
{
    const int b = blockIdx.x;
    if (b < 16) {
        int base = b * 1024;
        for (int i = base + threadIdx.x; i < base + 1024; i += 256) {
            int k = i / 64, c = i % 64;
            Wt1[c * 256 + k] = f2bf(W1[i]);
        }
    } else if (b < 18) {
        int base = (b - 16) * 1024;
        for (int i = base + threadIdx.x; i < base + 1024; i += 256) {
            int k = i / 32, c = i % 32;
            Wt2[c * 64 + k] = f2bf(W2[i]);
        }
    } else if (b == 18) {
        for (int i = threadIdx.x; i < 512; i += 256) {
            int k = i / 16, c = i % 16;
            Wt3[c * 32 + k] = f2bf(W3[i]);
        }
    } else {
        if (threadIdx.x < nbkt) bcursor[threadIdx.x] = threadIdx.x * CAP;
        if (threadIdx.x < 16) pooled[threadIdx.x] = 0.f;
    }
}

// ---------------------------------------------------------------- bucketed scatter
// packed edge: (dst_local << 17) | src   (src < 2^17, dst_local < 2^9)
__global__ __launch_bounds__(TPB) void bucket_scatter(
    const int* __restrict__ src, const int* __restrict__ dst,
    int* __restrict__ bcursor, unsigned int* __restrict__ packed, int E, int nbkt)
{
    __shared__ unsigned int  spk[CHUNK];
    __shared__ unsigned char sbk[CHUNK];
    __shared__ int h[NB_MAX];
    __shared__ int base[NB_MAX];
    for (int c0 = blockIdx.x * CHUNK; c0 < E; c0 += gridDim.x * CHUNK) {
        int m = min(CHUNK, E - c0);
        for (int i = threadIdx.x; i < nbkt; i += TPB) h[i] = 0;
        __syncthreads();
        for (int i = threadIdx.x; i < m; i += TPB) {
            int d = dst[c0 + i];
            int s = src[c0 + i];
            int b = d >> BKT_SHIFT;
            spk[i] = ((unsigned)(d & (BKT_N - 1)) << 17) | (unsigned)s;
            sbk[i] = (unsigned char)b;
            atomicAdd(&h[b], 1);
        }
        __syncthreads();
        for (int i = threadIdx.x; i < nbkt; i += TPB) {
            int c = h[i];
            base[i] = c ? atomicAdd(&bcursor[i], c) : 0;
            h[i] = 0;
        }
        __syncthreads();
        for (int i = threadIdx.x; i < m; i += TPB) {
            int b = sbk[i];
            int pos = base[b] + atomicAdd(&h[b], 1);
            packed[pos] = spk[i];
        }
        __syncthreads();
    }
}

// ---------------------------------------------------------------- per-bucket CSR
// Bucket prefix re-derived locally from bcursor (196-int LDS scan) — no boff pass.
__global__ __launch_bounds__(256) void bucket_csr(
    const unsigned int* __restrict__ packed, const int* __restrict__ bcursor,
    int* __restrict__ off, float* __restrict__ dinv, int* __restrict__ ssrc,
    int n, int nbkt)
{
    const int b  = blockIdx.x;
    const int t  = threadIdx.x;
    const int p0 = b * CAP;
    const int v0 = b << BKT_SHIFT;
    const int nv = min(BKT_N, n - v0);

    __shared__ int stmp[256];
    int cval = (t < nbkt) ? (bcursor[t] - t * CAP) : 0;
    stmp[t] = cval; __syncthreads();
    for (int s = 1; s < 256; s <<= 1) {
        int x = (t >= s) ? stmp[t - s] : 0;
        __syncthreads();
        stmp[t] += x;
        __syncthreads();
    }
    const int e0  = (b == 0) ? 0 : stmp[b - 1];
    const int cnt = stmp[b] - e0;
    if (b == nbkt - 1 && t == 0) off[n] = stmp[nbkt - 1];
    __syncthreads();

    __shared__ int hist[BKT_N];
    __shared__ int cur[BKT_N];
    __shared__ int tmp[256];

    for (int i = t; i < nv; i += 256) hist[i] = 0;
    __syncthreads();
    for (int e = t; e < cnt; e += 256)
        atomicAdd(&hist[packed[p0 + e] >> 17], 1);
    __syncthreads();

    int a = (2 * t     < nv) ? hist[2 * t]     : 0;
    int c = (2 * t + 1 < nv) ? hist[2 * t + 1] : 0;
    int ps = a + c;
    tmp[t] = ps; __syncthreads();
    for (int s = 1; s < 256; s <<= 1) {
        int x = (t >= s) ? tmp[t - s] : 0;
        __syncthreads();
        tmp[t] += x;
        __syncthreads();
    }
    int ex = tmp[t] - ps;
    if (2 * t < nv) {
        cur[2 * t] = ex;
        off[v0 + 2 * t] = e0 + ex;
        dinv[v0 + 2 * t] = rsqrtf((float)a + 1.0f);
    }
    if (2 * t + 1 < nv) {
        cur[2 * t + 1] = ex + a;
        off[v0 + 2 * t + 1] = e0 + ex + a;
        dinv[v0 + 2 * t + 1] = rsqrtf((float)c + 1.0f);
    }
    __syncthreads();

    for (int e = t; e < cnt; e += 256) {
        unsigned p = packed[p0 + e];
        int dl = p >> 17;
        int s  = p & 0x1FFFF;
        int pos = atomicAdd(&cur[dl], 1);
        ssrc[e0 + pos] = s;
    }
}

// ---------------------------------------------------------------- MFMA GEMM
// Yq = fp8((A@W)*dinv[row]*Y_SCALE), row-major [n][NCOL].
// 64 rows/block, 4 waves, each wave = one 16-row M-tile (high occupancy).
template<int K, int NCOL, typename AT>
__global__ __launch_bounds__(TPB) void gemm_mfma(
    const AT* __restrict__ A, const unsigned short* __restrict__ Wt,
    const float* __restrict__ dinv, unsigned char* __restrict__ Yq, int n)
{
    constexpr int NT = NCOL / 16;
    constexpr int KS = K / 32;
    const int lane = threadIdx.x & 63;
    const int w    = threadIdx.x >> 6;
    const int rowbase = blockIdx.x * 64 + w * 16;
    const int arow = lane & 15;
    const int kb   = (lane >> 4) * 8;

    f32x4 acc[NT];
#pragma unroll
    for (int nt = 0; nt < NT; nt++) acc[nt] = (f32x4)(0.f);

#pragma unroll
    for (int ks = 0; ks < KS; ks++) {
        bf16x8 a;
        int r = rowbase + arow;
        if constexpr (sizeof(AT) == 4) {
            if (r < n) {
                const float4* p = (const float4*)(A + (size_t)r * K + ks * 32 + kb);
                float4 u = p[0], v = p[1];
                a[0] = f2bf(u.x); a[1] = f2bf(u.y);
                a[2] = f2bf(u.z); a[3] = f2bf(u.w);
                a[4] = f2bf(v.x); a[5] = f2bf(v.y);
                a[6] = f2bf(v.z); a[7] = f2bf(v.w);
            } else {
#pragma unroll
                for (int i = 0; i < 8; i++) a[i] = 0;
            }
        } else {
            if (r < n)
                a = *(const bf16x8*)(A + (size_t)r * K + ks * 32 + kb);
            else {
#pragma unroll
                for (int i = 0; i < 8; i++) a[i] = 0;
            }
        }
        bf16x8 b[NT];
#pragma unroll
        for (int nt = 0; nt < NT; nt++)
            b[nt] = *(const bf16x8*)(Wt + (size_t)(nt * 16 + arow) * K + ks * 32 + kb);
#pragma unroll
        for (int nt = 0; nt < NT; nt++)
            acc[nt] = __builtin_amdgcn_mfma_f32_16x16x32_bf16(a, b[nt], acc[nt], 0, 0, 0);
    }

    int r0 = rowbase + (lane >> 4) * 4;
#pragma unroll
    for (int j = 0; j < 4; j++) {
        int r = r0 + j;
        if (r < n) {
            float dv = dinv[r] * Y_SCALE;
#pragma unroll
            for (int nt = 0; nt < NT; nt++)
                Yq[(size_t)r * NCOL + nt * 16 + arow] = f2fp8(acc[nt][j] * dv);
        }
    }
}

// ---------------------------------------- group-per-node aggregation (fp8 rows)
// G = F/16 lanes per node; one 64B granule per edge; 2*G edges (8 gathers) in flight.
template<int F>
__global__ __launch_bounds__(TPB) void seg_group(
    const int* __restrict__ off, const int* __restrict__ ssrc,
    const unsigned char* __restrict__ Yq, const float* __restrict__ dinv,
    const float* __restrict__ bias, unsigned int* __restrict__ H, int n)
{
    constexpr int G     = F / 16;                // lanes per node (4 or 2)
    constexpr int LOG2G = (G == 4) ? 2 : 1;
    const int lane  = threadIdx.x & 63;
    const int fl    = lane & (G - 1);
    const int gbase = lane & ~(G - 1);
    const int v     = (blockIdx.x * TPB + threadIdx.x) >> LOG2G;

    if (v >= n) return;

    float acc[16];
#pragma unroll
    for (int i = 0; i < 16; i++) acc[i] = 0.f;

    // self loop
    {
        uint4 q = *(const uint4*)(Yq + (size_t)v * F + fl * 16);
        acc_word(acc + 0, q.x); acc_word(acc + 4, q.y);
        acc_word(acc + 8, q.z); acc_word(acc + 12, q.w);
    }

    const int e0 = off[v], e1 = off[v + 1];
    int e = e0;
    for (; e + 2 * G <= e1; e += 2 * G) {
        int idx0 = ssrc[e + fl];
        int idx1 = ssrc[e + G + fl];
        uint4 q[2 * G];
#pragma unroll
        for (int k = 0; k < G; k++) {
            int sj = __shfl(idx0, gbase + k, 64);
            q[k] = *(const uint4*)(Yq + (size_t)sj * F + fl * 16);
        }
#pragma unroll
        for (int k = 0; k < G; k++) {
            int sj = __shfl(idx1, gbase + k, 64);
            q[G + k] = *(const uint4*)(Yq + (size_t)sj * F + fl * 16);
        }
#pragma unroll
        for (int k = 0; k < 2 * G; k++) {
            acc_word(acc + 0, q[k].x); acc_word(acc + 4, q[k].y);
            acc_word(acc + 8, q[k].z); acc_word(acc + 12, q[k].w);
        }
    }
    for (; e + G <= e1; e += G) {
        int idx = ssrc[e + fl];
        uint4 q[G];
#pragma unroll
        for (int k = 0; k < G; k++) {
            int sj = __shfl(idx, gbase + k, 64);
            q[k] = *(const uint4*)(Yq + (size_t)sj * F + fl * 16);
        }
#pragma unroll
        for (int k = 0; k < G; k++) {
            acc_word(acc + 0, q[k].x); acc_word(acc + 4, q[k].y);
            acc_word(acc + 8, q[k].z); acc_word(acc + 12, q[k].w);
        }
    }
    int rem = e1 - e;
    if (rem > 0) {
        int idx = (fl < rem) ? ssrc[e + fl] : 0;
        for (int k = 0; k < rem; k++) {
            int sj = __shfl(idx, gbase + k, 64);
            uint4 q = *(const uint4*)(Yq + (size_t)sj * F + fl * 16);
            acc_word(acc + 0, q.x); acc_word(acc + 4, q.y);
            acc_word(acc + 8, q.z); acc_word(acc + 12, q.w);
        }
    }

    float dv = dinv[v] * Y_INV_SCALE;
    unsigned hw[8];
#pragma unroll
    for (int i = 0; i < 16; i += 2) {
        float rx = fmaxf(fmaf(acc[i],     dv, bias[fl * 16 + i]),     0.f);
        float ry = fmaxf(fmaf(acc[i + 1], dv, bias[fl * 16 + i + 1]), 0.f);
        hw[i / 2] = ((unsigned)f2bf(ry) << 16) | (unsigned)f2bf(rx);
    }
    unsigned int* hp = H + (size_t)v * (F / 2) + fl * 8;
    *(uint4*)(hp + 0) = make_uint4(hw[0], hw[1], hw[2], hw[3]);
    *(uint4*)(hp + 4) = make_uint4(hw[4], hw[5], hw[6], hw[7]);
}

// ---------------------------------------- layer-3: lane-per-node (16B row), fused pool
__global__ __launch_bounds__(TPB) void seg_pool16(
    const int* __restrict__ off, const int* __restrict__ ssrc,
    const unsigned char* __restrict__ Yq, const float* __restrict__ dinv,
    const float* __restrict__ bias, float* __restrict__ pooled, int n)
{
    constexpr int U = 8;
    const int v = blockIdx.x * TPB + threadIdx.x;

    float r16[16];
#pragma unroll
    for (int i = 0; i < 16; i++) r16[i] = 0.f;

    if (v < n) {
        float acc[16];
#pragma unroll
        for (int i = 0; i < 16; i++) acc[i] = 0.f;

        {
            uint4 q = *(const uint4*)(Yq + (size_t)v * 16);
            acc_word(acc + 0, q.x); acc_word(acc + 4, q.y);
            acc_word(acc + 8, q.z); acc_word(acc + 12, q.w);
        }
        int e0 = off[v], e1 = off[v + 1];
        int e = e0;
        for (; e + U <= e1; e += U) {
            uint4 q[U];
#pragma unroll
            for (int k = 0; k < U; k++)
                q[k] = *(const uint4*)(Yq + (size_t)ssrc[e + k] * 16);
#pragma unroll
            for (int k = 0; k < U; k++) {
                acc_word(acc + 0, q[k].x); acc_word(acc + 4, q[k].y);
                acc_word(acc + 8, q[k].z); acc_word(acc + 12, q[k].w);
            }
        }
        for (; e < e1; e++) {
            uint4 q = *(const uint4*)(Yq + (size_t)ssrc[e] * 16);
            acc_word(acc + 0, q.x); acc_word(acc + 4, q.y);
            acc_word(acc + 8, q.z); acc_word(acc + 12, q.w);
        }

        float dv = dinv[v] * Y_INV_SCALE;
#pragma unroll
        for (int i = 0; i < 16; i++)
            r16[i] = fmaxf(fmaf(acc[i], dv, bias[i]), 0.f);
    }

    __shared__ float red[TPB][17];
#pragma unroll
    for (int i = 0; i < 16; i++) red[threadIdx.x][i] = r16[i];
    __syncthreads();
    for (int st = 128; st >= 1; st >>= 1) {
        if (threadIdx.x < st) {
#pragma unroll
            for (int i = 0; i < 16; i++)
                red[threadIdx.x][i] += red[threadIdx.x + st][i];
        }
        __syncthreads();
    }
    if (threadIdx.x < 16) atomicAdd(&pooled[threadIdx.x], red[0][threadIdx.x]);
}

// --------------------------------------------------- tiny MLP head + logsoftmax
__global__ void head_kernel(const float* __restrict__ pooled,
                            const float* __restrict__ Wf, const float* __restrict__ bf,
                            const float* __restrict__ Ws, const float* __restrict__ bs,
                            float* __restrict__ out, float invn)
{
    if (threadIdx.x == 0 && blockIdx.x == 0) {
        float p[16], h[8], s[10];
        for (int i = 0; i < 16; i++) p[i] = pooled[i] * invn;
        for (int j = 0; j < 8; j++) {
            float a = bf[j];
            for (int i = 0; i < 16; i++) a = fmaf(p[i], Wf[i * 8 + j], a);
            h[j] = fmaxf(a, 0.f);
        }
        float m = -1e30f;
        for (int c = 0; c < 10; c++) {
            float a = bs[c];
            for (int j = 0; j < 8; j++) a = fmaf(h[j], Ws[j * 10 + c], a);
            s[c] = a;
            m = fmaxf(m, a);
        }
        float lse = 0.f;
        for (int c = 0; c < 10; c++) lse += expf(s[c] - m);
        lse = logf(lse) + m;
        for (int c = 0; c < 10; c++) out[c] = s[c] - lse;
    }
}

static inline size_t align_up(size_t x) { return (x + 255) & ~(size_t)255; }

extern "C" void kernel_launch(void* const* d_in, const int* in_sizes, int n_in,
                              void* d_out, int out_size, void* d_ws, size_t ws_size,
                              hipStream_t stream)
{
    const float* X  = (const float*)d_in[0];
    const int*   ei = (const int*)  d_in[1];
    const float* W1 = (const float*)d_in[2];  const float* b1 = (const float*)d_in[3];
    const float* W2 = (const float*)d_in[4];  const float* b2 = (const float*)d_in[5];
    const float* W3 = (const float*)d_in[6];  const float* b3 = (const float*)d_in[7];
    const float* Wf = (const float*)d_in[8];  const float* bf = (const float*)d_in[9];
    const float* Ws = (const float*)d_in[10]; const float* bs = (const float*)d_in[11];

    const int n = in_sizes[0] / 256;
    const int E = in_sizes[1] / 2;
    const int* src = ei;
    const int* dst = ei + E;
    const int nbkt = (n + BKT_N - 1) / BKT_N;

    // workspace layout
    char* ws = (char*)d_ws;
    size_t off_b = 0;
    int* bcursor = (int*)(ws + off_b);   off_b += align_up(NB_MAX * 4);
    float* dinv  = (float*)(ws + off_b); off_b += align_up((size_t)n * 4);
    int* off     = (int*)(ws + off_b);   off_b += align_up((size_t)(n + 1) * 4);
    float* pooled= (float*)(ws + off_b); off_b += align_up(16 * 4);
    unsigned short* Wt1 = (unsigned short*)(ws + off_b); off_b += align_up(64 * 256 * 2);
    unsigned short* Wt2 = (unsigned short*)(ws + off_b); off_b += align_up(32 * 64 * 2);
    unsigned short* Wt3 = (unsigned short*)(ws + off_b); off_b += align_up(16 * 32 * 2);
    unsigned int* packed = (unsigned int*)(ws + off_b); off_b += align_up((size_t)nbkt * CAP * 4);
    int* ssrc    = (int*)(ws + off_b);   off_b += align_up((size_t)E * 4);
    unsigned char* Yq = (unsigned char*)(ws + off_b); off_b += align_up((size_t)n * 64);
    unsigned int* H = (unsigned int*)(ws + off_b); off_b += align_up((size_t)n * 64 * 2);

    // setup (W conversions, cursor init, pooled=0) + graph preprocessing
    setup_kernel<<<20, 256, 0, stream>>>(W1, Wt1, W2, Wt2, W3, Wt3, bcursor, pooled, nbkt);
    int nchunk = (E + CHUNK - 1) / CHUNK;
    bucket_scatter<<<nchunk, TPB, 0, stream>>>(src, dst, bcursor, packed, E, nbkt);
    bucket_csr<<<nbkt, 256, 0, stream>>>(packed, bcursor, off, dinv, ssrc, n, nbkt);

    const int gblk = (n + 63) / 64;
    const int nblk = (n + TPB - 1) / TPB;

    // ---- layer 1: 256 -> 64
    gemm_mfma<256, 64, float><<<gblk, TPB, 0, stream>>>(X, Wt1, dinv, Yq, n);
    seg_group<64><<<(4 * n + TPB - 1) / TPB, TPB, 0, stream>>>(off, ssrc, Yq, dinv, b1, H, n);

    // ---- layer 2: 64 -> 32
    gemm_mfma<64, 32, unsigned short><<<gblk, TPB, 0, stream>>>(
        (const unsigned short*)H, Wt2, dinv, Yq, n);
    seg_group<32><<<(2 * n + TPB - 1) / TPB, TPB, 0, stream>>>(off, ssrc, Yq, dinv, b2, H, n);

    // ---- layer 3: 32 -> 16 (fused pool)
    gemm_mfma<32, 16, unsigned short><<<gblk, TPB, 0, stream>>>(
        (const unsigned short*)H, Wt3, dinv, Yq, n);
    seg_pool16<<<nblk, TPB, 0, stream>>>(off, ssrc, Yq, dinv, b3, pooled, n);

    head_kernel<<<1, 64, 0, stream>>>(pooled, Wf, bf, Ws, bs, (float*)d_out, 1.0f / (float)n);
}

// Round 15
// 245.055 us; speedup vs baseline: 1.0764x; 1.0764x over previous
//
#include <hip/hip_runtime.h>
#include <hip/hip_fp16.h>
#include <math.h>

#define TPB 256
#define BKT_SHIFT 9
#define BKT_N 512              // nodes per bucket
#define NB_MAX 256             // max buckets (n <= 131072)
#define CHUNK 4096             // edges per block-chunk in bucket_scatter
#define CAP   24576            // padded packed-region capacity per bucket
#define Y_SCALE 16.0f
#define Y_INV_SCALE (1.0f / 16.0f)

typedef short bf16x8 __attribute__((ext_vector_type(8)));
typedef float f32x4  __attribute__((ext_vector_type(4)));

static __device__ inline unsigned short f2bf(float f) {
    union { float f; unsigned u; } v; v.f = f;
    unsigned r = v.u + 0x7FFF + ((v.u >> 16) & 1);
    return (unsigned short)(r >> 16);
}

static __device__ inline unsigned char f2fp8(float x) {
    int p = __builtin_amdgcn_cvt_pk_fp8_f32(x, x, 0, false);
    return (unsigned char)(p & 0xFF);
}

static __device__ inline void acc_word(float* a, unsigned u) {
    a[0] += __builtin_amdgcn_cvt_f32_fp8(u, 0);
    a[1] += __builtin_amdgcn_cvt_f32_fp8(u, 1);
    a[2] += __builtin_amdgcn_cvt_f32_fp8(u, 2);
    a[3] += __builtin_amdgcn_cvt_f32_fp8(u, 3);
}

// ------------------------------------------- setup: W->bf16^T x3, cursor init, pooled=0
__global__ __launch_bounds__(256) void setup_kernel(
    const float* __restrict__ W1, unsigned short* __restrict__ Wt1,
    const float* __restrict__ W2, unsigned short* __restrict__ Wt2,
    const float* __restrict__ W3, unsigned short* __restrict__ Wt3,
    int* __restrict__ bcursor, float* __restrict__ pooled, int nbkt)
{
    const int b = blockIdx.x;
    if (b < 16) {
        int base = b * 1024;
        for (int i = base + threadIdx.x; i < base + 1024; i += 256) {
            int k = i / 64, c = i % 64;
            Wt1[c * 256 + k] = f2bf(W1[i]);
        }
    } else if (b < 18) {
        int base = (b - 16) * 1024;
        for (int i = base + threadIdx.x; i < base + 1024; i += 256) {
            int k = i / 32, c = i % 32;
            Wt2[c * 64 + k] = f2bf(W2[i]);
        }
    } else if (b == 18) {
        for (int i = threadIdx.x; i < 512; i += 256) {
            int k = i / 16, c = i % 16;
            Wt3[c * 32 + k] = f2bf(W3[i]);
        }
    } else {
        if (threadIdx.x < nbkt) bcursor[threadIdx.x] = threadIdx.x * CAP;
        if (threadIdx.x < 16) pooled[threadIdx.x] = 0.f;
    }
}

// ---------------------------------------------------------------- bucketed scatter
// packed edge: (dst_local << 17) | src   (src < 2^17, dst_local < 2^9)
__global__ __launch_bounds__(TPB) void bucket_scatter(
    const int* __restrict__ src, const int* __restrict__ dst,
    int* __restrict__ bcursor, unsigned int* __restrict__ packed, int E, int nbkt)
{
    __shared__ unsigned int  spk[CHUNK];
    __shared__ unsigned char sbk[CHUNK];
    __shared__ int h[NB_MAX];
    __shared__ int base[NB_MAX];
    for (int c0 = blockIdx.x * CHUNK; c0 < E; c0 += gridDim.x * CHUNK) {
        int m = min(CHUNK, E - c0);
        for (int i = threadIdx.x; i < nbkt; i += TPB) h[i] = 0;
        __syncthreads();
        for (int i = threadIdx.x; i < m; i += TPB) {
            int d = dst[c0 + i];
            int s = src[c0 + i];
            int b = d >> BKT_SHIFT;
            spk[i] = ((unsigned)(d & (BKT_N - 1)) << 17) | (unsigned)s;
            sbk[i] = (unsigned char)b;
            atomicAdd(&h[b], 1);
        }
        __syncthreads();
        for (int i = threadIdx.x; i < nbkt; i += TPB) {
            int c = h[i];
            base[i] = c ? atomicAdd(&bcursor[i], c) : 0;
            h[i] = 0;
        }
        __syncthreads();
        for (int i = threadIdx.x; i < m; i += TPB) {
            int b = sbk[i];
            int pos = base[b] + atomicAdd(&h[b], 1);
            packed[pos] = spk[i];
        }
        __syncthreads();
    }
}

// ---------------------------------------------------------------- per-bucket CSR
// Bucket prefix re-derived locally from bcursor (196-int LDS scan) — no boff pass.
__global__ __launch_bounds__(256) void bucket_csr(
    const unsigned int* __restrict__ packed, const int* __restrict__ bcursor,
    int* __restrict__ off, float* __restrict__ dinv, int* __restrict__ ssrc,
    int n, int nbkt)
{
    const int b  = blockIdx.x;
    const int t  = threadIdx.x;
    const int p0 = b * CAP;
    const int v0 = b << BKT_SHIFT;
    const int nv = min(BKT_N, n - v0);

    __shared__ int stmp[256];
    int cval = (t < nbkt) ? (bcursor[t] - t * CAP) : 0;
    stmp[t] = cval; __syncthreads();
    for (int s = 1; s < 256; s <<= 1) {
        int x = (t >= s) ? stmp[t - s] : 0;
        __syncthreads();
        stmp[t] += x;
        __syncthreads();
    }
    const int e0  = (b == 0) ? 0 : stmp[b - 1];
    const int cnt = stmp[b] - e0;
    if (b == nbkt - 1 && t == 0) off[n] = stmp[nbkt - 1];
    __syncthreads();

    __shared__ int hist[BKT_N];
    __shared__ int cur[BKT_N];
    __shared__ int tmp[256];

    for (int i = t; i < nv; i += 256) hist[i] = 0;
    __syncthreads();
    for (int e = t; e < cnt; e += 256)
        atomicAdd(&hist[packed[p0 + e] >> 17], 1);
    __syncthreads();

    int a = (2 * t     < nv) ? hist[2 * t]     : 0;
    int c = (2 * t + 1 < nv) ? hist[2 * t + 1] : 0;
    int ps = a + c;
    tmp[t] = ps; __syncthreads();
    for (int s = 1; s < 256; s <<= 1) {
        int x = (t >= s) ? tmp[t - s] : 0;
        __syncthreads();
        tmp[t] += x;
        __syncthreads();
    }
    int ex = tmp[t] - ps;
    if (2 * t < nv) {
        cur[2 * t] = ex;
        off[v0 + 2 * t] = e0 + ex;
        dinv[v0 + 2 * t] = rsqrtf((float)a + 1.0f);
    }
    if (2 * t + 1 < nv) {
        cur[2 * t + 1] = ex + a;
        off[v0 + 2 * t + 1] = e0 + ex + a;
        dinv[v0 + 2 * t + 1] = rsqrtf((float)c + 1.0f);
    }
    __syncthreads();

    for (int e = t; e < cnt; e += 256) {
        unsigned p = packed[p0 + e];
        int dl = p >> 17;
        int s  = p & 0x1FFFF;
        int pos = atomicAdd(&cur[dl], 1);
        ssrc[e0 + pos] = s;
    }
}

// ---------------------------------------------------------------- MFMA GEMM
// Yq = fp8((A@W)*dinv[row]*Y_SCALE), row-major [n][NCOL].
template<int K, int NCOL, typename AT>
__global__ __launch_bounds__(TPB) void gemm_mfma(
    const AT* __restrict__ A, const unsigned short* __restrict__ Wt,
    const float* __restrict__ dinv, unsigned char* __restrict__ Yq, int n)
{
    constexpr int NT = NCOL / 16;
    constexpr int KS = K / 32;
    const int lane = threadIdx.x & 63;
    const int w    = threadIdx.x >> 6;
    const int rowbase = blockIdx.x * 128 + w * 32;
    const int arow = lane & 15;
    const int kb   = (lane >> 4) * 8;

    f32x4 acc[2][NT];
#pragma unroll
    for (int mt = 0; mt < 2; mt++)
#pragma unroll
        for (int nt = 0; nt < NT; nt++) acc[mt][nt] = (f32x4)(0.f);

#pragma unroll
    for (int ks = 0; ks < KS; ks++) {
        bf16x8 a[2];
#pragma unroll
        for (int mt = 0; mt < 2; mt++) {
            int r = rowbase + mt * 16 + arow;
            if constexpr (sizeof(AT) == 4) {
                if (r < n) {
                    const float4* p = (const float4*)(A + (size_t)r * K + ks * 32 + kb);
                    float4 u = p[0], v = p[1];
                    a[mt][0] = f2bf(u.x); a[mt][1] = f2bf(u.y);
                    a[mt][2] = f2bf(u.z); a[mt][3] = f2bf(u.w);
                    a[mt][4] = f2bf(v.x); a[mt][5] = f2bf(v.y);
                    a[mt][6] = f2bf(v.z); a[mt][7] = f2bf(v.w);
                } else {
#pragma unroll
                    for (int i = 0; i < 8; i++) a[mt][i] = 0;
                }
            } else {
                if (r < n)
                    a[mt] = *(const bf16x8*)(A + (size_t)r * K + ks * 32 + kb);
                else {
#pragma unroll
                    for (int i = 0; i < 8; i++) a[mt][i] = 0;
                }
            }
        }
        bf16x8 b[NT];
#pragma unroll
        for (int nt = 0; nt < NT; nt++)
            b[nt] = *(const bf16x8*)(Wt + (size_t)(nt * 16 + arow) * K + ks * 32 + kb);
#pragma unroll
        for (int mt = 0; mt < 2; mt++)
#pragma unroll
            for (int nt = 0; nt < NT; nt++)
                acc[mt][nt] = __builtin_amdgcn_mfma_f32_16x16x32_bf16(
                    a[mt], b[nt], acc[mt][nt], 0, 0, 0);
    }

#pragma unroll
    for (int mt = 0; mt < 2; mt++) {
        int r0 = rowbase + mt * 16 + (lane >> 4) * 4;
#pragma unroll
        for (int j = 0; j < 4; j++) {
            int r = r0 + j;
            if (r < n) {
                float dv = dinv[r] * Y_SCALE;
#pragma unroll
                for (int nt = 0; nt < NT; nt++)
                    Yq[(size_t)r * NCOL + nt * 16 + arow] = f2fp8(acc[mt][nt][j] * dv);
            }
        }
    }
}

// ---------------------------------------- group-per-node aggregation (fp8 rows)
// G = F/16 lanes per node; one 64B granule per edge. Main loop processes 2*G
// edges per iteration -> 8 gathers in flight.
template<int F>
__global__ __launch_bounds__(TPB) void seg_group(
    const int* __restrict__ off, const int* __restrict__ ssrc,
    const unsigned char* __restrict__ Yq, const float* __restrict__ dinv,
    const float* __restrict__ bias, unsigned int* __restrict__ H, int n)
{
    constexpr int G     = F / 16;                // lanes per node (4 or 2)
    constexpr int LOG2G = (G == 4) ? 2 : 1;
    const int lane  = threadIdx.x & 63;
    const int fl    = lane & (G - 1);
    const int gbase = lane & ~(G - 1);
    const int v     = (blockIdx.x * TPB + threadIdx.x) >> LOG2G;

    if (v >= n) return;

    float acc[16];
#pragma unroll
    for (int i = 0; i < 16; i++) acc[i] = 0.f;

    // self loop
    {
        uint4 q = *(const uint4*)(Yq + (size_t)v * F + fl * 16);
        acc_word(acc + 0, q.x); acc_word(acc + 4, q.y);
        acc_word(acc + 8, q.z); acc_word(acc + 12, q.w);
    }

    const int e0 = off[v], e1 = off[v + 1];
    int e = e0;
    for (; e + 2 * G <= e1; e += 2 * G) {
        int idx0 = ssrc[e + fl];
        int idx1 = ssrc[e + G + fl];
        uint4 q[2 * G];
#pragma unroll
        for (int k = 0; k < G; k++) {
            int sj = __shfl(idx0, gbase + k, 64);
            q[k] = *(const uint4*)(Yq + (size_t)sj * F + fl * 16);
        }
#pragma unroll
        for (int k = 0; k < G; k++) {
            int sj = __shfl(idx1, gbase + k, 64);
            q[G + k] = *(const uint4*)(Yq + (size_t)sj * F + fl * 16);
        }
#pragma unroll
        for (int k = 0; k < 2 * G; k++) {
            acc_word(acc + 0, q[k].x); acc_word(acc + 4, q[k].y);
            acc_word(acc + 8, q[k].z); acc_word(acc + 12, q[k].w);
        }
    }
    for (; e + G <= e1; e += G) {
        int idx = ssrc[e + fl];
        uint4 q[G];
#pragma unroll
        for (int k = 0; k < G; k++) {
            int sj = __shfl(idx, gbase + k, 64);
            q[k] = *(const uint4*)(Yq + (size_t)sj * F + fl * 16);
        }
#pragma unroll
        for (int k = 0; k < G; k++) {
            acc_word(acc + 0, q[k].x); acc_word(acc + 4, q[k].y);
            acc_word(acc + 8, q[k].z); acc_word(acc + 12, q[k].w);
        }
    }
    int rem = e1 - e;
    if (rem > 0) {
        int idx = (fl < rem) ? ssrc[e + fl] : 0;
        for (int k = 0; k < rem; k++) {
            int sj = __shfl(idx, gbase + k, 64);
            uint4 q = *(const uint4*)(Yq + (size_t)sj * F + fl * 16);
            acc_word(acc + 0, q.x); acc_word(acc + 4, q.y);
            acc_word(acc + 8, q.z); acc_word(acc + 12, q.w);
        }
    }

    float dv = dinv[v] * Y_INV_SCALE;
    unsigned hw[8];
#pragma unroll
    for (int i = 0; i < 16; i += 2) {
        float rx = fmaxf(fmaf(acc[i],     dv, bias[fl * 16 + i]),     0.f);
        float ry = fmaxf(fmaf(acc[i + 1], dv, bias[fl * 16 + i + 1]), 0.f);
        hw[i / 2] = ((unsigned)f2bf(ry) << 16) | (unsigned)f2bf(rx);
    }
    unsigned int* hp = H + (size_t)v * (F / 2) + fl * 8;
    *(uint4*)(hp + 0) = make_uint4(hw[0], hw[1], hw[2], hw[3]);
    *(uint4*)(hp + 4) = make_uint4(hw[4], hw[5], hw[6], hw[7]);
}

// ---------------------------------------- layer-3: lane-per-node (16B row), fused pool
__global__ __launch_bounds__(TPB) void seg_pool16(
    const int* __restrict__ off, const int* __restrict__ ssrc,
    const unsigned char* __restrict__ Yq, const float* __restrict__ dinv,
    const float* __restrict__ bias, float* __restrict__ pooled, int n)
{
    constexpr int U = 8;
    const int v = blockIdx.x * TPB + threadIdx.x;

    float r16[16];
#pragma unroll
    for (int i = 0; i < 16; i++) r16[i] = 0.f;

    if (v < n) {
        float acc[16];
#pragma unroll
        for (int i = 0; i < 16; i++) acc[i] = 0.f;

        {
            uint4 q = *(const uint4*)(Yq + (size_t)v * 16);
            acc_word(acc + 0, q.x); acc_word(acc + 4, q.y);
            acc_word(acc + 8, q.z); acc_word(acc + 12, q.w);
        }
        int e0 = off[v], e1 = off[v + 1];
        int e = e0;
        for (; e + U <= e1; e += U) {
            uint4 q[U];
#pragma unroll
            for (int k = 0; k < U; k++)
                q[k] = *(const uint4*)(Yq + (size_t)ssrc[e + k] * 16);
#pragma unroll
            for (int k = 0; k < U; k++) {
                acc_word(acc + 0, q[k].x); acc_word(acc + 4, q[k].y);
                acc_word(acc + 8, q[k].z); acc_word(acc + 12, q[k].w);
            }
        }
        for (; e < e1; e++) {
            uint4 q = *(const uint4*)(Yq + (size_t)ssrc[e] * 16);
            acc_word(acc + 0, q.x); acc_word(acc + 4, q.y);
            acc_word(acc + 8, q.z); acc_word(acc + 12, q.w);
        }

        float dv = dinv[v] * Y_INV_SCALE;
#pragma unroll
        for (int i = 0; i < 16; i++)
            r16[i] = fmaxf(fmaf(acc[i], dv, bias[i]), 0.f);
    }

    __shared__ float red[TPB][17];
#pragma unroll
    for (int i = 0; i < 16; i++) red[threadIdx.x][i] = r16[i];
    __syncthreads();
    for (int st = 128; st >= 1; st >>= 1) {
        if (threadIdx.x < st) {
#pragma unroll
            for (int i = 0; i < 16; i++)
                red[threadIdx.x][i] += red[threadIdx.x + st][i];
        }
        __syncthreads();
    }
    if (threadIdx.x < 16) atomicAdd(&pooled[threadIdx.x], red[0][threadIdx.x]);
}

// --------------------------------------------------- tiny MLP head + logsoftmax
__global__ void head_kernel(const float* __restrict__ pooled,
                            const float* __restrict__ Wf, const float* __restrict__ bf,
                            const float* __restrict__ Ws, const float* __restrict__ bs,
                            float* __restrict__ out, float invn)
{
    if (threadIdx.x == 0 && blockIdx.x == 0) {
        float p[16], h[8], s[10];
        for (int i = 0; i < 16; i++) p[i] = pooled[i] * invn;
        for (int j = 0; j < 8; j++) {
            float a = bf[j];
            for (int i = 0; i < 16; i++) a = fmaf(p[i], Wf[i * 8 + j], a);
            h[j] = fmaxf(a, 0.f);
        }
        float m = -1e30f;
        for (int c = 0; c < 10; c++) {
            float a = bs[c];
            for (int j = 0; j < 8; j++) a = fmaf(h[j], Ws[j * 10 + c], a);
            s[c] = a;
            m = fmaxf(m, a);
        }
        float lse = 0.f;
        for (int c = 0; c < 10; c++) lse += expf(s[c] - m);
        lse = logf(lse) + m;
        for (int c = 0; c < 10; c++) out[c] = s[c] - lse;
    }
}

static inline size_t align_up(size_t x) { return (x + 255) & ~(size_t)255; }

extern "C" void kernel_launch(void* const* d_in, const int* in_sizes, int n_in,
                              void* d_out, int out_size, void* d_ws, size_t ws_size,
                              hipStream_t stream)
{
    const float* X  = (const float*)d_in[0];
    const int*   ei = (const int*)  d_in[1];
    const float* W1 = (const float*)d_in[2];  const float* b1 = (const float*)d_in[3];
    const float* W2 = (const float*)d_in[4];  const float* b2 = (const float*)d_in[5];
    const float* W3 = (const float*)d_in[6];  const float* b3 = (const float*)d_in[7];
    const float* Wf = (const float*)d_in[8];  const float* bf = (const float*)d_in[9];
    const float* Ws = (const float*)d_in[10]; const float* bs = (const float*)d_in[11];

    const int n = in_sizes[0] / 256;
    const int E = in_sizes[1] / 2;
    const int* src = ei;
    const int* dst = ei + E;
    const int nbkt = (n + BKT_N - 1) / BKT_N;

    // workspace layout
    char* ws = (char*)d_ws;
    size_t off_b = 0;
    int* bcursor = (int*)(ws + off_b);   off_b += align_up(NB_MAX * 4);
    float* dinv  = (float*)(ws + off_b); off_b += align_up((size_t)n * 4);
    int* off     = (int*)(ws + off_b);   off_b += align_up((size_t)(n + 1) * 4);
    float* pooled= (float*)(ws + off_b); off_b += align_up(16 * 4);
    unsigned short* Wt1 = (unsigned short*)(ws + off_b); off_b += align_up(64 * 256 * 2);
    unsigned short* Wt2 = (unsigned short*)(ws + off_b); off_b += align_up(32 * 64 * 2);
    unsigned short* Wt3 = (unsigned short*)(ws + off_b); off_b += align_up(16 * 32 * 2);
    unsigned int* packed = (unsigned int*)(ws + off_b); off_b += align_up((size_t)nbkt * CAP * 4);
    int* ssrc    = (int*)(ws + off_b);   off_b += align_up((size_t)E * 4);
    unsigned char* Yq = (unsigned char*)(ws + off_b); off_b += align_up((size_t)n * 64);
    unsigned int* H = (unsigned int*)(ws + off_b); off_b += align_up((size_t)n * 64 * 2);

    // setup (W conversions, cursor init, pooled=0) + graph preprocessing
    setup_kernel<<<20, 256, 0, stream>>>(W1, Wt1, W2, Wt2, W3, Wt3, bcursor, pooled, nbkt);
    int nchunk = (E + CHUNK - 1) / CHUNK;
    bucket_scatter<<<nchunk, TPB, 0, stream>>>(src, dst, bcursor, packed, E, nbkt);
    bucket_csr<<<nbkt, 256, 0, stream>>>(packed, bcursor, off, dinv, ssrc, n, nbkt);

    const int gblk = (n + 127) / 128;
    const int nblk = (n + TPB - 1) / TPB;

    // ---- layer 1: 256 -> 64
    gemm_mfma<256, 64, float><<<gblk, TPB, 0, stream>>>(X, Wt1, dinv, Yq, n);
    seg_group<64><<<(4 * n + TPB - 1) / TPB, TPB, 0, stream>>>(off, ssrc, Yq, dinv, b1, H, n);

    // ---- layer 2: 64 -> 32
    gemm_mfma<64, 32, unsigned short><<<gblk, TPB, 0, stream>>>(
        (const unsigned short*)H, Wt2, dinv, Yq, n);
    seg_group<32><<<(2 * n + TPB - 1) / TPB, TPB, 0, stream>>>(off, ssrc, Yq, dinv, b2, H, n);

    // ---- layer 3: 32 -> 16 (fused pool)
    gemm_mfma<32, 16, unsigned short><<<gblk, TPB, 0, stream>>>(
        (const unsigned short*)H, Wt3, dinv, Yq, n);
    seg_pool16<<<nblk, TPB, 0, stream>>>(off, ssrc, Yq, dinv, b3, pooled, n);

    head_kernel<<<1, 64, 0, stream>>>(pooled, Wf, bf, Ws, bs, (float*)d_out, 1.0f / (float)n);
}